// Round 1
// baseline (684.934 us; speedup 1.0000x reference)
//
#include <hip/hip_runtime.h>
#include <cstddef>

#define H_IN 1024
#define W_IN 1024
#define BN_EPS 1e-5f

__device__ __forceinline__ void atomicMaxF(float* addr, float val) {
    if (val >= 0.0f) {
        atomicMax((int*)addr, __float_as_int(val));
    } else {
        atomicMin((unsigned int*)addr, __float_as_uint(val));
    }
}

// ---------------- stage 0: BEV init + rasterize ----------------
__global__ void k_init_bev(float* __restrict__ bev) {
    size_t i = (size_t)blockIdx.x * blockDim.x + threadIdx.x;
    int plane = (int)((i >> 20) & 1);   // H*W = 2^20
    bev[i] = plane == 0 ? -10.0f : 0.0f;
}

__global__ void k_rasterize(const float* __restrict__ pts, float* __restrict__ bev, int n) {
    int i = blockIdx.x * blockDim.x + threadIdx.x;
    if (i >= n) return;
    float fb  = pts[(size_t)i*5+0];
    float px  = pts[(size_t)i*5+1];
    float py  = pts[(size_t)i*5+2];
    float pz  = pts[(size_t)i*5+3];
    float pit = pts[(size_t)i*5+4];
    const float XS = (float)(1024.0/69.12);
    const float YS = (float)(1024.0/79.36);
    int xp = (int)(px * XS);                  // trunc toward zero, same as astype(int32)
    int yp = (int)((py + 39.68f) * YS);
    if (xp < 0 || xp >= W_IN || yp < 0 || yp >= H_IN) return;
    int b = (int)fb;
    size_t off = (size_t)(b*2) * (H_IN*(size_t)W_IN) + (size_t)yp*W_IN + xp;
    atomicMaxF(bev + off, pz);
    atomicMaxF(bev + off + (size_t)H_IN*W_IN, pit);
}

// ---------------- stage 1: conv1(2->8,3x3,pad1)+BN+ReLU+maxpool2 ----------------
// in:  bev [4,2,1024,1024]   out: x1 [4,8,512,512]
__global__ void k_conv1(const float* __restrict__ bev, const float* __restrict__ w0,
                        const float* __restrict__ b0, const float* __restrict__ g0,
                        const float* __restrict__ be0, const float* __restrict__ m0,
                        const float* __restrict__ v0, float* __restrict__ out) {
    __shared__ float wS[144];       // [8][2][3][3]
    __shared__ float sS[8], tS[8];
    int t = threadIdx.x;
    if (t < 144) wS[t] = w0[t];
    if (t < 8) {
        float s = g0[t] / sqrtf(v0[t] + BN_EPS);
        sS[t] = s;
        tS[t] = (b0[t] - m0[t]) * s + be0[t];
    }
    __syncthreads();
    int idx = blockIdx.x * 256 + t;                 // 4*512*512 total
    int x = idx & 511, y = (idx >> 9) & 511, b = idx >> 18;
    const float* base = bev + (size_t)b * 2 * H_IN * W_IN;
    float in[2][4][4];
    #pragma unroll
    for (int c = 0; c < 2; c++)
        #pragma unroll
        for (int r = 0; r < 4; r++) {
            int iy = 2*y - 1 + r;
            #pragma unroll
            for (int cc = 0; cc < 4; cc++) {
                int ix = 2*x - 1 + cc;
                in[c][r][cc] = (iy >= 0 && iy < H_IN && ix >= 0 && ix < W_IN)
                    ? base[(size_t)c*H_IN*W_IN + (size_t)iy*W_IN + ix] : 0.0f;
            }
        }
    float* ob = out + (size_t)b * 8 * 512 * 512 + (size_t)y*512 + x;
    #pragma unroll
    for (int oc = 0; oc < 8; oc++) {
        float mx = 0.0f;                            // post-ReLU values are >= 0
        #pragma unroll
        for (int py = 0; py < 2; py++)
            #pragma unroll
            for (int px = 0; px < 2; px++) {
                float acc = 0.0f;
                #pragma unroll
                for (int c = 0; c < 2; c++)
                    #pragma unroll
                    for (int kh = 0; kh < 3; kh++)
                        #pragma unroll
                        for (int kw = 0; kw < 3; kw++)
                            acc += in[c][py+kh][px+kw] * wS[((oc*2+c)*3+kh)*3+kw];
                acc = fmaxf(acc * sS[oc] + tS[oc], 0.0f);
                mx = fmaxf(mx, acc);
            }
        ob[(size_t)oc*512*512] = mx;
    }
}

// ---------------- stage 2: conv2 grouped(8)+BN+ReLU+maxpool2 ----------------
// in: x1 [4,8,512,512]   out: x2 [4,16,256,256]   (oc reads ic = oc>>1)
__global__ void k_conv2(const float* __restrict__ x1, const float* __restrict__ w1,
                        const float* __restrict__ b1, const float* __restrict__ g1,
                        const float* __restrict__ be1, const float* __restrict__ m1,
                        const float* __restrict__ v1, float* __restrict__ out) {
    __shared__ float wS[144];       // [16][3][3]
    __shared__ float sS[16], tS[16];
    int t = threadIdx.x;
    if (t < 144) wS[t] = w1[t];
    if (t < 16) {
        float s = g1[t] / sqrtf(v1[t] + BN_EPS);
        sS[t] = s;
        tS[t] = (b1[t] - m1[t]) * s + be1[t];
    }
    __syncthreads();
    int idx = blockIdx.x * 256 + t;                 // 4*256*256 total
    int x = idx & 255, y = (idx >> 8) & 255, b = idx >> 16;
    const float* base = x1 + (size_t)b * 8 * 512 * 512;
    float* ob = out + (size_t)b * 16 * 256 * 256 + (size_t)y*256 + x;
    #pragma unroll
    for (int g = 0; g < 8; g++) {
        float p[4][4];
        #pragma unroll
        for (int r = 0; r < 4; r++) {
            int iy = 2*y - 1 + r;
            #pragma unroll
            for (int c = 0; c < 4; c++) {
                int ix = 2*x - 1 + c;
                p[r][c] = (iy >= 0 && iy < 512 && ix >= 0 && ix < 512)
                    ? base[(size_t)g*512*512 + (size_t)iy*512 + ix] : 0.0f;
            }
        }
        #pragma unroll
        for (int sub = 0; sub < 2; sub++) {
            int oc = g*2 + sub;
            float mx = 0.0f;
            #pragma unroll
            for (int py = 0; py < 2; py++)
                #pragma unroll
                for (int px = 0; px < 2; px++) {
                    float acc = 0.0f;
                    #pragma unroll
                    for (int kh = 0; kh < 3; kh++)
                        #pragma unroll
                        for (int kw = 0; kw < 3; kw++)
                            acc += p[py+kh][px+kw] * wS[(oc*3+kh)*3+kw];
                    acc = fmaxf(acc * sS[oc] + tS[oc], 0.0f);
                    mx = fmaxf(mx, acc);
                }
            ob[(size_t)oc*256*256] = mx;
        }
    }
}

// ---------------- stage 3: depthwise + (shuffle=identity) + pointwise + BN + ReLU ----------------
// in: x2 [4,16,256,256]   out: x3 [4,32,256,256]
__global__ void k_dwpw(const float* __restrict__ x2, const float* __restrict__ wdw,
                       const float* __restrict__ bdw, const float* __restrict__ wpw,
                       const float* __restrict__ bpw, const float* __restrict__ g2,
                       const float* __restrict__ be2, const float* __restrict__ m2,
                       const float* __restrict__ v2, float* __restrict__ out) {
    __shared__ float wdwS[144];     // [16][3][3]
    __shared__ float bdwS[16];
    __shared__ float wpwS[512];     // [32][16]
    __shared__ float sS[32], tS[32];
    int t = threadIdx.x;
    if (t < 144) wdwS[t] = wdw[t];
    if (t < 16) bdwS[t] = bdw[t];
    for (int i = t; i < 512; i += 256) wpwS[i] = wpw[i];
    if (t < 32) {
        float s = g2[t] / sqrtf(v2[t] + BN_EPS);
        sS[t] = s;
        tS[t] = (bpw[t] - m2[t]) * s + be2[t];
    }
    __syncthreads();
    int idx = blockIdx.x * 256 + t;                 // 4*256*256 total
    int x = idx & 255, y = (idx >> 8) & 255, b = idx >> 16;
    const float* base = x2 + (size_t)b * 16 * 256 * 256;
    float acc[32];
    #pragma unroll
    for (int oc = 0; oc < 32; oc++) acc[oc] = 0.0f;
    #pragma unroll
    for (int ic = 0; ic < 16; ic++) {
        float d = bdwS[ic];
        #pragma unroll
        for (int kh = 0; kh < 3; kh++) {
            int iy = y - 1 + kh;
            #pragma unroll
            for (int kw = 0; kw < 3; kw++) {
                int ix = x - 1 + kw;
                float v = (iy >= 0 && iy < 256 && ix >= 0 && ix < 256)
                    ? base[(size_t)ic*256*256 + (size_t)iy*256 + ix] : 0.0f;
                d += v * wdwS[(ic*3+kh)*3+kw];
            }
        }
        #pragma unroll
        for (int oc = 0; oc < 32; oc++) acc[oc] += d * wpwS[oc*16+ic];
    }
    float* ob = out + (size_t)b * 32 * 256 * 256 + (size_t)y*256 + x;
    #pragma unroll
    for (int oc = 0; oc < 32; oc++)
        ob[(size_t)oc*256*256] = fmaxf(acc[oc]*sS[oc] + tS[oc], 0.0f);
}

// ---------------- stage 4: conv3(32->64,3x3,pad1)+BN+ReLU+maxpool2 ----------------
// in: x3 [4,32,256,256]   out: d_out [4,64,128,128]
// block = 256 thr = 16x16 pooled pixels; blockIdx = tileX(8) + 8*tileY(8) + 64*(ocg(8) + 8*b(4))
__global__ void k_conv3(const float* __restrict__ x3, const float* __restrict__ w3,
                        const float* __restrict__ b3, const float* __restrict__ g3,
                        const float* __restrict__ be3, const float* __restrict__ m3,
                        const float* __restrict__ v3, float* __restrict__ out) {
    __shared__ float wS[2304];          // 8 oc x 32 ic x 9
    __shared__ float sS[8], tS[8];
    __shared__ float patch[34*34];
    int t = threadIdx.x;
    int bidx = blockIdx.x;
    int tileX = bidx & 7, tileY = (bidx >> 3) & 7;
    int bo = bidx >> 6, ocg = bo & 7, b = bo >> 3;
    const float* wsrc = w3 + (size_t)ocg * 8 * 32 * 9;
    for (int i = t; i < 2304; i += 256) wS[i] = wsrc[i];
    if (t < 8) {
        int oc = ocg*8 + t;
        float s = g3[oc] / sqrtf(v3[oc] + BN_EPS);
        sS[t] = s;
        tS[t] = (b3[oc] - m3[oc]) * s + be3[oc];
    }
    int tx = t & 15, ty = t >> 4;
    int ox = tileX*16 + tx, oy = tileY*16 + ty;     // pooled coords 0..127
    int ix0 = tileX*32 - 1, iy0 = tileY*32 - 1;     // patch origin in 256-grid
    const float* base = x3 + (size_t)b * 32 * 256 * 256;
    float acc[8][4];
    #pragma unroll
    for (int oc = 0; oc < 8; oc++)
        #pragma unroll
        for (int q = 0; q < 4; q++) acc[oc][q] = 0.0f;

    for (int ic = 0; ic < 32; ic++) {
        __syncthreads();
        for (int i = t; i < 34*34; i += 256) {
            int r = i / 34, c = i % 34;
            int iy = iy0 + r, ix = ix0 + c;
            patch[i] = (iy >= 0 && iy < 256 && ix >= 0 && ix < 256)
                ? base[(size_t)ic*65536 + (size_t)iy*256 + ix] : 0.0f;
        }
        __syncthreads();
        float p[4][4];
        #pragma unroll
        for (int r = 0; r < 4; r++)
            #pragma unroll
            for (int c = 0; c < 4; c++)
                p[r][c] = patch[(2*ty + r)*34 + 2*tx + c];
        #pragma unroll
        for (int oc = 0; oc < 8; oc++) {
            const float* wp = &wS[(oc*32 + ic)*9];
            float w0_ = wp[0], w1_ = wp[1], w2_ = wp[2];
            float w3_ = wp[3], w4_ = wp[4], w5_ = wp[5];
            float w6_ = wp[6], w7_ = wp[7], w8_ = wp[8];
            #pragma unroll
            for (int py = 0; py < 2; py++)
                #pragma unroll
                for (int px = 0; px < 2; px++) {
                    float a = p[py  ][px]*w0_ + p[py  ][px+1]*w1_ + p[py  ][px+2]*w2_
                            + p[py+1][px]*w3_ + p[py+1][px+1]*w4_ + p[py+1][px+2]*w5_
                            + p[py+2][px]*w6_ + p[py+2][px+1]*w7_ + p[py+2][px+2]*w8_;
                    acc[oc][py*2+px] += a;
                }
        }
    }
    #pragma unroll
    for (int oc = 0; oc < 8; oc++) {
        float m = 0.0f;
        #pragma unroll
        for (int q = 0; q < 4; q++)
            m = fmaxf(m, fmaxf(acc[oc][q]*sS[oc] + tS[oc], 0.0f));
        out[(((size_t)b*64 + ocg*8 + oc)*128 + oy)*128 + ox] = m;
    }
}

extern "C" void kernel_launch(void* const* d_in, const int* in_sizes, int n_in,
                              void* d_out, int out_size, void* d_ws, size_t ws_size,
                              hipStream_t stream) {
    const float* points = (const float*)d_in[0];
    int n = in_sizes[0] / 5;
    const float* w0  = (const float*)d_in[2];
    const float* b0  = (const float*)d_in[3];
    const float* g0  = (const float*)d_in[4];
    const float* be0 = (const float*)d_in[5];
    const float* m0  = (const float*)d_in[6];
    const float* v0  = (const float*)d_in[7];
    const float* w1  = (const float*)d_in[8];
    const float* b1  = (const float*)d_in[9];
    const float* g1  = (const float*)d_in[10];
    const float* be1 = (const float*)d_in[11];
    const float* m1  = (const float*)d_in[12];
    const float* v1  = (const float*)d_in[13];
    const float* wdw = (const float*)d_in[14];
    const float* bdw = (const float*)d_in[15];
    const float* wpw = (const float*)d_in[16];
    const float* bpw = (const float*)d_in[17];
    const float* g2  = (const float*)d_in[18];
    const float* be2 = (const float*)d_in[19];
    const float* m2  = (const float*)d_in[20];
    const float* v2  = (const float*)d_in[21];
    const float* w3  = (const float*)d_in[22];
    const float* b3  = (const float*)d_in[23];
    const float* g3  = (const float*)d_in[24];
    const float* be3 = (const float*)d_in[25];
    const float* m3  = (const float*)d_in[26];
    const float* v3  = (const float*)d_in[27];

    float* ws  = (float*)d_ws;
    float* bev = ws;                 // [4,2,1024,1024]  8,388,608 f
    float* x1  = ws + 8388608;       // [4,8,512,512]    8,388,608 f
    float* x2  = bev;                // [4,16,256,256]   4,194,304 f (reuse)
    float* x3  = x1;                 // [4,32,256,256]   8,388,608 f (reuse)
    float* outp = (float*)d_out;     // [4,64,128,128]

    k_init_bev<<<32768, 256, 0, stream>>>(bev);
    k_rasterize<<<(n + 255)/256, 256, 0, stream>>>(points, bev, n);
    k_conv1<<<4096, 256, 0, stream>>>(bev, w0, b0, g0, be0, m0, v0, x1);
    k_conv2<<<1024, 256, 0, stream>>>(x1, w1, b1, g1, be1, m1, v1, x2);
    k_dwpw<<<1024, 256, 0, stream>>>(x2, wdw, bdw, wpw, bpw, g2, be2, m2, v2, x3);
    k_conv3<<<2048, 256, 0, stream>>>(x3, w3, b3, g3, be3, m3, v3, outp);
}

// Round 2
// 390.475 us; speedup vs baseline: 1.7541x; 1.7541x over previous
//
#include <hip/hip_runtime.h>
#include <cstddef>

#define H_IN 1024
#define W_IN 1024
#define BN_EPS 1e-5f

__device__ __forceinline__ void atomicMaxF(float* addr, float val) {
    if (val >= 0.0f) {
        atomicMax((int*)addr, __float_as_int(val));
    } else {
        atomicMin((unsigned int*)addr, __float_as_uint(val));
    }
}

// ---------------- stage 0: BEV init + rasterize ----------------
__global__ void k_init_bev(float* __restrict__ bev) {
    size_t i = (size_t)blockIdx.x * blockDim.x + threadIdx.x;
    int plane = (int)((i >> 20) & 1);   // H*W = 2^20
    bev[i] = plane == 0 ? -10.0f : 0.0f;
}

__global__ void k_rasterize(const float* __restrict__ pts, float* __restrict__ bev, int n) {
    int i = blockIdx.x * blockDim.x + threadIdx.x;
    if (i >= n) return;
    float fb  = pts[(size_t)i*5+0];
    float px  = pts[(size_t)i*5+1];
    float py  = pts[(size_t)i*5+2];
    float pz  = pts[(size_t)i*5+3];
    float pit = pts[(size_t)i*5+4];
    const float XS = (float)(1024.0/69.12);
    const float YS = (float)(1024.0/79.36);
    int xp = (int)(px * XS);                  // trunc toward zero, same as astype(int32)
    int yp = (int)((py + 39.68f) * YS);
    if (xp < 0 || xp >= W_IN || yp < 0 || yp >= H_IN) return;
    int b = (int)fb;
    size_t off = (size_t)(b*2) * (H_IN*(size_t)W_IN) + (size_t)yp*W_IN + xp;
    atomicMaxF(bev + off, pz);
    atomicMaxF(bev + off + (size_t)H_IN*W_IN, pit);
}

// ---------------- stage 1: conv1(2->8,3x3,pad1)+BN+ReLU+maxpool2 ----------------
// in:  bev [4,2,1024,1024]   out: x1 [4,8,512,512]
__global__ void k_conv1(const float* __restrict__ bev, const float* __restrict__ w0,
                        const float* __restrict__ b0, const float* __restrict__ g0,
                        const float* __restrict__ be0, const float* __restrict__ m0,
                        const float* __restrict__ v0, float* __restrict__ out) {
    __shared__ float wS[144];       // [8][2][3][3]
    __shared__ float sS[8], tS[8];
    int t = threadIdx.x;
    if (t < 144) wS[t] = w0[t];
    if (t < 8) {
        float s = g0[t] / sqrtf(v0[t] + BN_EPS);
        sS[t] = s;
        tS[t] = (b0[t] - m0[t]) * s + be0[t];
    }
    __syncthreads();
    int idx = blockIdx.x * 256 + t;                 // 4*512*512 total
    int x = idx & 511, y = (idx >> 9) & 511, b = idx >> 18;
    const float* base = bev + (size_t)b * 2 * H_IN * W_IN;
    float in[2][4][4];
    #pragma unroll
    for (int c = 0; c < 2; c++)
        #pragma unroll
        for (int r = 0; r < 4; r++) {
            int iy = 2*y - 1 + r;
            #pragma unroll
            for (int cc = 0; cc < 4; cc++) {
                int ix = 2*x - 1 + cc;
                in[c][r][cc] = (iy >= 0 && iy < H_IN && ix >= 0 && ix < W_IN)
                    ? base[(size_t)c*H_IN*W_IN + (size_t)iy*W_IN + ix] : 0.0f;
            }
        }
    float* ob = out + (size_t)b * 8 * 512 * 512 + (size_t)y*512 + x;
    #pragma unroll
    for (int oc = 0; oc < 8; oc++) {
        float mx = 0.0f;                            // post-ReLU values are >= 0
        #pragma unroll
        for (int py = 0; py < 2; py++)
            #pragma unroll
            for (int px = 0; px < 2; px++) {
                float acc = 0.0f;
                #pragma unroll
                for (int c = 0; c < 2; c++)
                    #pragma unroll
                    for (int kh = 0; kh < 3; kh++)
                        #pragma unroll
                        for (int kw = 0; kw < 3; kw++)
                            acc += in[c][py+kh][px+kw] * wS[((oc*2+c)*3+kh)*3+kw];
                acc = fmaxf(acc * sS[oc] + tS[oc], 0.0f);
                mx = fmaxf(mx, acc);
            }
        ob[(size_t)oc*512*512] = mx;
    }
}

// ---------------- stage 2: conv2 grouped(8)+BN+ReLU+maxpool2 ----------------
// in: x1 [4,8,512,512]   out: x2 [4,16,256,256]   (oc reads ic = oc>>1)
__global__ void k_conv2(const float* __restrict__ x1, const float* __restrict__ w1,
                        const float* __restrict__ b1, const float* __restrict__ g1,
                        const float* __restrict__ be1, const float* __restrict__ m1,
                        const float* __restrict__ v1, float* __restrict__ out) {
    __shared__ float wS[144];       // [16][3][3]
    __shared__ float sS[16], tS[16];
    int t = threadIdx.x;
    if (t < 144) wS[t] = w1[t];
    if (t < 16) {
        float s = g1[t] / sqrtf(v1[t] + BN_EPS);
        sS[t] = s;
        tS[t] = (b1[t] - m1[t]) * s + be1[t];
    }
    __syncthreads();
    int idx = blockIdx.x * 256 + t;                 // 4*256*256 total
    int x = idx & 255, y = (idx >> 8) & 255, b = idx >> 16;
    const float* base = x1 + (size_t)b * 8 * 512 * 512;
    float* ob = out + (size_t)b * 16 * 256 * 256 + (size_t)y*256 + x;
    #pragma unroll
    for (int g = 0; g < 8; g++) {
        float p[4][4];
        #pragma unroll
        for (int r = 0; r < 4; r++) {
            int iy = 2*y - 1 + r;
            #pragma unroll
            for (int c = 0; c < 4; c++) {
                int ix = 2*x - 1 + c;
                p[r][c] = (iy >= 0 && iy < 512 && ix >= 0 && ix < 512)
                    ? base[(size_t)g*512*512 + (size_t)iy*512 + ix] : 0.0f;
            }
        }
        #pragma unroll
        for (int sub = 0; sub < 2; sub++) {
            int oc = g*2 + sub;
            float mx = 0.0f;
            #pragma unroll
            for (int py = 0; py < 2; py++)
                #pragma unroll
                for (int px = 0; px < 2; px++) {
                    float acc = 0.0f;
                    #pragma unroll
                    for (int kh = 0; kh < 3; kh++)
                        #pragma unroll
                        for (int kw = 0; kw < 3; kw++)
                            acc += p[py+kh][px+kw] * wS[(oc*3+kh)*3+kw];
                    acc = fmaxf(acc * sS[oc] + tS[oc], 0.0f);
                    mx = fmaxf(mx, acc);
                }
            ob[(size_t)oc*256*256] = mx;
        }
    }
}

// ---------------- stage 3: depthwise + (shuffle=identity) + pointwise + BN + ReLU ----------------
// in: x2 [4,16,256,256]   out: x3 [4,32,256,256]
// Restructured vs round 0: compute dv[16] (depthwise) first, then per-oc scalar
// accumulate + immediate store. No 32-wide live accumulator array -> no scratch spill.
__global__ void k_dwpw(const float* __restrict__ x2, const float* __restrict__ wdw,
                       const float* __restrict__ bdw, const float* __restrict__ wpw,
                       const float* __restrict__ bpw, const float* __restrict__ g2,
                       const float* __restrict__ be2, const float* __restrict__ m2,
                       const float* __restrict__ v2, float* __restrict__ out) {
    __shared__ float wdwS[144];     // [16][3][3]
    __shared__ float bdwS[16];
    __shared__ float wpwS[512];     // [32][16]
    __shared__ float sS[32], tS[32];
    int t = threadIdx.x;
    if (t < 144) wdwS[t] = wdw[t];
    if (t < 16) bdwS[t] = bdw[t];
    for (int i = t; i < 512; i += 256) wpwS[i] = wpw[i];
    if (t < 32) {
        float s = g2[t] / sqrtf(v2[t] + BN_EPS);
        sS[t] = s;
        tS[t] = (bpw[t] - m2[t]) * s + be2[t];
    }
    __syncthreads();
    int idx = blockIdx.x * 256 + t;                 // 4*256*256 total
    int x = idx & 255, y = (idx >> 8) & 255, b = idx >> 16;
    const float* base = x2 + (size_t)b * 16 * 256 * 256;

    // depthwise: 16 values, fully static indexing -> registers
    float dv[16];
    #pragma unroll
    for (int ic = 0; ic < 16; ic++) {
        float d = bdwS[ic];
        #pragma unroll
        for (int kh = 0; kh < 3; kh++) {
            int iy = y - 1 + kh;
            #pragma unroll
            for (int kw = 0; kw < 3; kw++) {
                int ix = x - 1 + kw;
                float v = (iy >= 0 && iy < 256 && ix >= 0 && ix < 256)
                    ? base[(size_t)ic*256*256 + (size_t)iy*256 + ix] : 0.0f;
                d += v * wdwS[(ic*3+kh)*3+kw];
            }
        }
        dv[ic] = d;
    }

    // pointwise: one scalar accumulator at a time, store immediately
    float* ob = out + (size_t)b * 32 * 256 * 256 + (size_t)y*256 + x;
    #pragma unroll
    for (int oc = 0; oc < 32; oc++) {
        float a = 0.0f;
        #pragma unroll
        for (int ic = 0; ic < 16; ic++)
            a += dv[ic] * wpwS[oc*16+ic];
        ob[(size_t)oc*256*256] = fmaxf(a*sS[oc] + tS[oc], 0.0f);
    }
}

// ---------------- stage 4: conv3(32->64,3x3,pad1)+BN+ReLU+maxpool2 ----------------
// in: x3 [4,32,256,256]   out: d_out [4,64,128,128]
// block = 256 thr = 16x16 pooled pixels; blockIdx = tileX(8) + 8*tileY(8) + 64*(ocg(8) + 8*b(4))
__global__ void k_conv3(const float* __restrict__ x3, const float* __restrict__ w3,
                        const float* __restrict__ b3, const float* __restrict__ g3,
                        const float* __restrict__ be3, const float* __restrict__ m3,
                        const float* __restrict__ v3, float* __restrict__ out) {
    __shared__ float wS[2304];          // 8 oc x 32 ic x 9
    __shared__ float sS[8], tS[8];
    __shared__ float patch[34*34];
    int t = threadIdx.x;
    int bidx = blockIdx.x;
    int tileX = bidx & 7, tileY = (bidx >> 3) & 7;
    int bo = bidx >> 6, ocg = bo & 7, b = bo >> 3;
    const float* wsrc = w3 + (size_t)ocg * 8 * 32 * 9;
    for (int i = t; i < 2304; i += 256) wS[i] = wsrc[i];
    if (t < 8) {
        int oc = ocg*8 + t;
        float s = g3[oc] / sqrtf(v3[oc] + BN_EPS);
        sS[t] = s;
        tS[t] = (b3[oc] - m3[oc]) * s + be3[oc];
    }
    int tx = t & 15, ty = t >> 4;
    int ox = tileX*16 + tx, oy = tileY*16 + ty;     // pooled coords 0..127
    int ix0 = tileX*32 - 1, iy0 = tileY*32 - 1;     // patch origin in 256-grid
    const float* base = x3 + (size_t)b * 32 * 256 * 256;
    float acc[8][4];
    #pragma unroll
    for (int oc = 0; oc < 8; oc++)
        #pragma unroll
        for (int q = 0; q < 4; q++) acc[oc][q] = 0.0f;

    for (int ic = 0; ic < 32; ic++) {
        __syncthreads();
        for (int i = t; i < 34*34; i += 256) {
            int r = i / 34, c = i % 34;
            int iy = iy0 + r, ix = ix0 + c;
            patch[i] = (iy >= 0 && iy < 256 && ix >= 0 && ix < 256)
                ? base[(size_t)ic*65536 + (size_t)iy*256 + ix] : 0.0f;
        }
        __syncthreads();
        float p[4][4];
        #pragma unroll
        for (int r = 0; r < 4; r++)
            #pragma unroll
            for (int c = 0; c < 4; c++)
                p[r][c] = patch[(2*ty + r)*34 + 2*tx + c];
        #pragma unroll
        for (int oc = 0; oc < 8; oc++) {
            const float* wp = &wS[(oc*32 + ic)*9];
            float w0_ = wp[0], w1_ = wp[1], w2_ = wp[2];
            float w3_ = wp[3], w4_ = wp[4], w5_ = wp[5];
            float w6_ = wp[6], w7_ = wp[7], w8_ = wp[8];
            #pragma unroll
            for (int py = 0; py < 2; py++)
                #pragma unroll
                for (int px = 0; px < 2; px++) {
                    float a = p[py  ][px]*w0_ + p[py  ][px+1]*w1_ + p[py  ][px+2]*w2_
                            + p[py+1][px]*w3_ + p[py+1][px+1]*w4_ + p[py+1][px+2]*w5_
                            + p[py+2][px]*w6_ + p[py+2][px+1]*w7_ + p[py+2][px+2]*w8_;
                    acc[oc][py*2+px] += a;
                }
        }
    }
    #pragma unroll
    for (int oc = 0; oc < 8; oc++) {
        float m = 0.0f;
        #pragma unroll
        for (int q = 0; q < 4; q++)
            m = fmaxf(m, fmaxf(acc[oc][q]*sS[oc] + tS[oc], 0.0f));
        out[(((size_t)b*64 + ocg*8 + oc)*128 + oy)*128 + ox] = m;
    }
}

extern "C" void kernel_launch(void* const* d_in, const int* in_sizes, int n_in,
                              void* d_out, int out_size, void* d_ws, size_t ws_size,
                              hipStream_t stream) {
    const float* points = (const float*)d_in[0];
    int n = in_sizes[0] / 5;
    const float* w0  = (const float*)d_in[2];
    const float* b0  = (const float*)d_in[3];
    const float* g0  = (const float*)d_in[4];
    const float* be0 = (const float*)d_in[5];
    const float* m0  = (const float*)d_in[6];
    const float* v0  = (const float*)d_in[7];
    const float* w1  = (const float*)d_in[8];
    const float* b1  = (const float*)d_in[9];
    const float* g1  = (const float*)d_in[10];
    const float* be1 = (const float*)d_in[11];
    const float* m1  = (const float*)d_in[12];
    const float* v1  = (const float*)d_in[13];
    const float* wdw = (const float*)d_in[14];
    const float* bdw = (const float*)d_in[15];
    const float* wpw = (const float*)d_in[16];
    const float* bpw = (const float*)d_in[17];
    const float* g2  = (const float*)d_in[18];
    const float* be2 = (const float*)d_in[19];
    const float* m2  = (const float*)d_in[20];
    const float* v2  = (const float*)d_in[21];
    const float* w3  = (const float*)d_in[22];
    const float* b3  = (const float*)d_in[23];
    const float* g3  = (const float*)d_in[24];
    const float* be3 = (const float*)d_in[25];
    const float* m3  = (const float*)d_in[26];
    const float* v3  = (const float*)d_in[27];

    float* ws  = (float*)d_ws;
    float* bev = ws;                 // [4,2,1024,1024]  8,388,608 f
    float* x1  = ws + 8388608;       // [4,8,512,512]    8,388,608 f
    float* x2  = bev;                // [4,16,256,256]   4,194,304 f (reuse)
    float* x3  = x1;                 // [4,32,256,256]   8,388,608 f (reuse)
    float* outp = (float*)d_out;     // [4,64,128,128]

    k_init_bev<<<32768, 256, 0, stream>>>(bev);
    k_rasterize<<<(n + 255)/256, 256, 0, stream>>>(points, bev, n);
    k_conv1<<<4096, 256, 0, stream>>>(bev, w0, b0, g0, be0, m0, v0, x1);
    k_conv2<<<1024, 256, 0, stream>>>(x1, w1, b1, g1, be1, m1, v1, x2);
    k_dwpw<<<1024, 256, 0, stream>>>(x2, wdw, bdw, wpw, bpw, g2, be2, m2, v2, x3);
    k_conv3<<<2048, 256, 0, stream>>>(x3, w3, b3, g3, be3, m3, v3, outp);
}

// Round 4
// 291.241 us; speedup vs baseline: 2.3518x; 1.3407x over previous
//
#include <hip/hip_runtime.h>
#include <cstddef>

#define H_IN 1024
#define W_IN 1024
#define BN_EPS 1e-5f

typedef float f32x4 __attribute__((ext_vector_type(4)));
typedef _Float16 f16x8 __attribute__((ext_vector_type(8)));

__device__ __forceinline__ void atomicMaxF(float* addr, float val) {
    if (val >= 0.0f) {
        atomicMax((int*)addr, __float_as_int(val));
    } else {
        atomicMin((unsigned int*)addr, __float_as_uint(val));
    }
}

// ---------------- stage 0: BEV init + rasterize ----------------
__global__ void k_init_bev(float* __restrict__ bev) {
    size_t i = (size_t)blockIdx.x * blockDim.x + threadIdx.x;
    int plane = (int)((i >> 20) & 1);   // H*W = 2^20
    bev[i] = plane == 0 ? -10.0f : 0.0f;
}

__global__ void k_rasterize(const float* __restrict__ pts, float* __restrict__ bev, int n) {
    int i = blockIdx.x * blockDim.x + threadIdx.x;
    if (i >= n) return;
    float fb  = pts[(size_t)i*5+0];
    float px  = pts[(size_t)i*5+1];
    float py  = pts[(size_t)i*5+2];
    float pz  = pts[(size_t)i*5+3];
    float pit = pts[(size_t)i*5+4];
    const float XS = (float)(1024.0/69.12);
    const float YS = (float)(1024.0/79.36);
    int xp = (int)(px * XS);                  // trunc toward zero, same as astype(int32)
    int yp = (int)((py + 39.68f) * YS);
    if (xp < 0 || xp >= W_IN || yp < 0 || yp >= H_IN) return;
    int b = (int)fb;
    size_t off = (size_t)(b*2) * (H_IN*(size_t)W_IN) + (size_t)yp*W_IN + xp;
    atomicMaxF(bev + off, pz);
    atomicMaxF(bev + off + (size_t)H_IN*W_IN, pit);
}

// ---------------- stage 1: conv1(2->8,3x3,pad1)+BN+ReLU+maxpool2 ----------------
// in:  bev [4,2,1024,1024]   out: x1 [4,8,512,512]
__global__ void k_conv1(const float* __restrict__ bev, const float* __restrict__ w0,
                        const float* __restrict__ b0, const float* __restrict__ g0,
                        const float* __restrict__ be0, const float* __restrict__ m0,
                        const float* __restrict__ v0, float* __restrict__ out) {
    __shared__ float wS[144];       // [8][2][3][3]
    __shared__ float sS[8], tS[8];
    int t = threadIdx.x;
    if (t < 144) wS[t] = w0[t];
    if (t < 8) {
        float s = g0[t] / sqrtf(v0[t] + BN_EPS);
        sS[t] = s;
        tS[t] = (b0[t] - m0[t]) * s + be0[t];
    }
    __syncthreads();
    int idx = blockIdx.x * 256 + t;                 // 4*512*512 total
    int x = idx & 511, y = (idx >> 9) & 511, b = idx >> 18;
    const float* base = bev + (size_t)b * 2 * H_IN * W_IN;
    float in[2][4][4];
    #pragma unroll
    for (int c = 0; c < 2; c++)
        #pragma unroll
        for (int r = 0; r < 4; r++) {
            int iy = 2*y - 1 + r;
            #pragma unroll
            for (int cc = 0; cc < 4; cc++) {
                int ix = 2*x - 1 + cc;
                in[c][r][cc] = (iy >= 0 && iy < H_IN && ix >= 0 && ix < W_IN)
                    ? base[(size_t)c*H_IN*W_IN + (size_t)iy*W_IN + ix] : 0.0f;
            }
        }
    float* ob = out + (size_t)b * 8 * 512 * 512 + (size_t)y*512 + x;
    #pragma unroll
    for (int oc = 0; oc < 8; oc++) {
        float mx = 0.0f;                            // post-ReLU values are >= 0
        #pragma unroll
        for (int py = 0; py < 2; py++)
            #pragma unroll
            for (int px = 0; px < 2; px++) {
                float acc = 0.0f;
                #pragma unroll
                for (int c = 0; c < 2; c++)
                    #pragma unroll
                    for (int kh = 0; kh < 3; kh++)
                        #pragma unroll
                        for (int kw = 0; kw < 3; kw++)
                            acc += in[c][py+kh][px+kw] * wS[((oc*2+c)*3+kh)*3+kw];
                acc = fmaxf(acc * sS[oc] + tS[oc], 0.0f);
                mx = fmaxf(mx, acc);
            }
        ob[(size_t)oc*512*512] = mx;
    }
}

// ---------------- stage 2: conv2 grouped(8)+BN+ReLU+maxpool2 ----------------
// in: x1 [4,8,512,512]   out: x2 [4,16,256,256]   (oc reads ic = oc>>1)
__global__ void k_conv2(const float* __restrict__ x1, const float* __restrict__ w1,
                        const float* __restrict__ b1, const float* __restrict__ g1,
                        const float* __restrict__ be1, const float* __restrict__ m1,
                        const float* __restrict__ v1, float* __restrict__ out) {
    __shared__ float wS[144];       // [16][3][3]
    __shared__ float sS[16], tS[16];
    int t = threadIdx.x;
    if (t < 144) wS[t] = w1[t];
    if (t < 16) {
        float s = g1[t] / sqrtf(v1[t] + BN_EPS);
        sS[t] = s;
        tS[t] = (b1[t] - m1[t]) * s + be1[t];
    }
    __syncthreads();
    int idx = blockIdx.x * 256 + t;                 // 4*256*256 total
    int x = idx & 255, y = (idx >> 8) & 255, b = idx >> 16;
    const float* base = x1 + (size_t)b * 8 * 512 * 512;
    float* ob = out + (size_t)b * 16 * 256 * 256 + (size_t)y*256 + x;
    #pragma unroll
    for (int g = 0; g < 8; g++) {
        float p[4][4];
        #pragma unroll
        for (int r = 0; r < 4; r++) {
            int iy = 2*y - 1 + r;
            #pragma unroll
            for (int c = 0; c < 4; c++) {
                int ix = 2*x - 1 + c;
                p[r][c] = (iy >= 0 && iy < 512 && ix >= 0 && ix < 512)
                    ? base[(size_t)g*512*512 + (size_t)iy*512 + ix] : 0.0f;
            }
        }
        #pragma unroll
        for (int sub = 0; sub < 2; sub++) {
            int oc = g*2 + sub;
            float mx = 0.0f;
            #pragma unroll
            for (int py = 0; py < 2; py++)
                #pragma unroll
                for (int px = 0; px < 2; px++) {
                    float acc = 0.0f;
                    #pragma unroll
                    for (int kh = 0; kh < 3; kh++)
                        #pragma unroll
                        for (int kw = 0; kw < 3; kw++)
                            acc += p[py+kh][px+kw] * wS[(oc*3+kh)*3+kw];
                    acc = fmaxf(acc * sS[oc] + tS[oc], 0.0f);
                    mx = fmaxf(mx, acc);
                }
            ob[(size_t)oc*256*256] = mx;
        }
    }
}

// ---------------- stage 3: depthwise + pointwise + BN + ReLU -> f16 NHWC ----------------
// in: x2 [4,16,256,256] f32   out: x3h [4,256,256,32] f16
__global__ void k_dwpw(const float* __restrict__ x2, const float* __restrict__ wdw,
                       const float* __restrict__ bdw, const float* __restrict__ wpw,
                       const float* __restrict__ bpw, const float* __restrict__ g2,
                       const float* __restrict__ be2, const float* __restrict__ m2,
                       const float* __restrict__ v2, _Float16* __restrict__ out) {
    __shared__ float wdwS[144];     // [16][3][3]
    __shared__ float bdwS[16];
    __shared__ float wpwS[512];     // [32][16]
    __shared__ float sS[32], tS[32];
    int t = threadIdx.x;
    if (t < 144) wdwS[t] = wdw[t];
    if (t < 16) bdwS[t] = bdw[t];
    for (int i = t; i < 512; i += 256) wpwS[i] = wpw[i];
    if (t < 32) {
        float s = g2[t] / sqrtf(v2[t] + BN_EPS);
        sS[t] = s;
        tS[t] = (bpw[t] - m2[t]) * s + be2[t];
    }
    __syncthreads();
    int idx = blockIdx.x * 256 + t;                 // 4*256*256 total
    int x = idx & 255, y = (idx >> 8) & 255, b = idx >> 16;
    const float* base = x2 + (size_t)b * 16 * 256 * 256;

    // depthwise: 16 values, fully static indexing -> registers
    float dv[16];
    #pragma unroll
    for (int ic = 0; ic < 16; ic++) {
        float d = bdwS[ic];
        #pragma unroll
        for (int kh = 0; kh < 3; kh++) {
            int iy = y - 1 + kh;
            #pragma unroll
            for (int kw = 0; kw < 3; kw++) {
                int ix = x - 1 + kw;
                float v = (iy >= 0 && iy < 256 && ix >= 0 && ix < 256)
                    ? base[(size_t)ic*256*256 + (size_t)iy*256 + ix] : 0.0f;
                d += v * wdwS[(ic*3+kh)*3+kw];
            }
        }
        dv[ic] = d;
    }

    // pointwise -> f16 NHWC store (4x 16B)
    _Float16* ob = out + ((size_t)((b*256 + y)*256 + x)) * 32;
    f16x8 ov[4];
    #pragma unroll
    for (int oc = 0; oc < 32; oc++) {
        float a = 0.0f;
        #pragma unroll
        for (int ic = 0; ic < 16; ic++)
            a += dv[ic] * wpwS[oc*16+ic];
        ov[oc >> 3][oc & 7] = (_Float16)fmaxf(a*sS[oc] + tS[oc], 0.0f);
    }
    #pragma unroll
    for (int q = 0; q < 4; q++)
        *(f16x8*)(ob + q*8) = ov[q];
}

// ---------------- weight prep for conv3 MFMA ----------------
// wh[khw][oc][ic] f16 = w3[oc][ic][kh][kw] * s[oc];  tv[oc] = (b3-m3)*s + be3
__global__ void k_wprep(const float* __restrict__ w3, const float* __restrict__ b3,
                        const float* __restrict__ g3, const float* __restrict__ be3,
                        const float* __restrict__ m3, const float* __restrict__ v3,
                        _Float16* __restrict__ wh, float* __restrict__ tv) {
    int t = threadIdx.x;
    for (int i = t; i < 9*64*32; i += 256) {
        int khw = i >> 11;          // / (64*32)
        int rem = i & 2047;
        int oc = rem >> 5, ic = rem & 31;
        int kh = khw / 3, kw = khw % 3;
        float s = g3[oc] / sqrtf(v3[oc] + BN_EPS);
        wh[i] = (_Float16)(w3[((oc*32 + ic)*3 + kh)*3 + kw] * s);
    }
    if (t < 64) {
        float s = g3[t] / sqrtf(v3[t] + BN_EPS);
        tv[t] = (b3[t] - m3[t]) * s + be3[t];
    }
}

// ---------------- stage 4: conv3 via MFMA f16 implicit GEMM + BN + ReLU + maxpool2 ----------------
// in: x3h [4,256,256,32] f16 NHWC, wh [9][64][32] f16, tv[64] f32
// out: d_out [4,64,128,128] f32
// grid: 512 blocks = 4 xt * 32 yg * 4 b; block = 4 waves; each block: 4 y-pair tiles
// tile = pre-pool 2 rows x 64 cols; wave w owns x-slice [w*16, w*16+16)
__global__ __launch_bounds__(256, 2) void k_conv3m(const _Float16* __restrict__ xh,
                                                   const _Float16* __restrict__ wh,
                                                   const float* __restrict__ tv,
                                                   float* __restrict__ out) {
    __shared__ _Float16 As[4*66*40];        // rows x px x ic(pad 32->40), 21120 B
    int t = threadIdx.x;
    int lane = t & 63, w = t >> 6;
    int l15 = lane & 15, l4 = lane >> 4;
    int bi = blockIdx.x;
    int xt = bi & 3, yg = (bi >> 2) & 31, b = bi >> 7;
    int x0 = xt * 64;

    // B fragments: weights, held in VGPRs for the whole block (36 x f16x8 = 144 VGPR)
    f16x8 Bf[9][4];
    #pragma unroll
    for (int khw = 0; khw < 9; khw++)
        #pragma unroll
        for (int g = 0; g < 4; g++)
            Bf[khw][g] = *(const f16x8*)(wh + ((khw*64 + g*16 + l15)*32 + 8*l4));

    float tvv[4];
    #pragma unroll
    for (int g = 0; g < 4; g++) tvv[g] = tv[g*16 + l15];

    for (int ti = 0; ti < 4; ti++) {
        int ypool = yg*4 + ti;              // pooled row 0..127
        int y0 = ypool*2;
        __syncthreads();                    // wait: all waves done reading As (prev tile)
        // stage A: rows y0-1..y0+2, px 0..65 (global x = x0-1+px), 32 ic each
        for (int s = t; s < 264; s += 256) {
            int row = s / 66, px = s % 66;
            int gy = y0 - 1 + row, gx = x0 - 1 + px;
            float4* dst = (float4*)&As[(row*66 + px)*40];
            if (gy >= 0 && gy < 256 && gx >= 0 && gx < 256) {
                const float4* src = (const float4*)(xh + ((size_t)((b*256 + gy)*256 + gx)) * 32);
                #pragma unroll
                for (int j = 0; j < 4; j++) dst[j] = src[j];
            } else {
                float4 z = make_float4(0.f, 0.f, 0.f, 0.f);
                #pragma unroll
                for (int j = 0; j < 4; j++) dst[j] = z;
            }
        }
        __syncthreads();

        f32x4 acc[2][4];
        #pragma unroll
        for (int f = 0; f < 2; f++)
            #pragma unroll
            for (int g = 0; g < 4; g++)
                acc[f][g] = (f32x4){0.f, 0.f, 0.f, 0.f};

        #pragma unroll
        for (int kh = 0; kh < 3; kh++)
            #pragma unroll
            for (int kw = 0; kw < 3; kw++) {
                f16x8 Af[2];
                #pragma unroll
                for (int f = 0; f < 2; f++) {
                    int row = f + kh;                       // staged row idx
                    int px = w*16 + l15 + kw;               // staged px idx
                    Af[f] = *(const f16x8*)&As[(row*66 + px)*40 + 8*l4];
                }
                #pragma unroll
                for (int f = 0; f < 2; f++)
                    #pragma unroll
                    for (int g = 0; g < 4; g++)
                        acc[f][g] = __builtin_amdgcn_mfma_f32_16x16x32_f16(
                            Af[f], Bf[kh*3+kw][g], acc[f][g], 0, 0, 0);
            }

        // epilogue: bias + relu + 2x2 maxpool (all in-lane), store
        #pragma unroll
        for (int g = 0; g < 4; g++) {
            int oc = g*16 + l15;
            #pragma unroll
            for (int q = 0; q < 2; q++) {
                float v0 = fmaxf(fmaxf(acc[0][g][2*q]   + tvv[g], 0.f),
                                 fmaxf(acc[0][g][2*q+1] + tvv[g], 0.f));
                float v1 = fmaxf(fmaxf(acc[1][g][2*q]   + tvv[g], 0.f),
                                 fmaxf(acc[1][g][2*q+1] + tvv[g], 0.f));
                int px = x0/2 + w*8 + 2*l4 + q;
                out[(((size_t)b*64 + oc)*128 + ypool)*128 + px] = fmaxf(v0, v1);
            }
        }
    }
}

extern "C" void kernel_launch(void* const* d_in, const int* in_sizes, int n_in,
                              void* d_out, int out_size, void* d_ws, size_t ws_size,
                              hipStream_t stream) {
    const float* points = (const float*)d_in[0];
    int n = in_sizes[0] / 5;
    const float* w0  = (const float*)d_in[2];
    const float* b0  = (const float*)d_in[3];
    const float* g0  = (const float*)d_in[4];
    const float* be0 = (const float*)d_in[5];
    const float* m0  = (const float*)d_in[6];
    const float* v0  = (const float*)d_in[7];
    const float* w1  = (const float*)d_in[8];
    const float* b1  = (const float*)d_in[9];
    const float* g1  = (const float*)d_in[10];
    const float* be1 = (const float*)d_in[11];
    const float* m1  = (const float*)d_in[12];
    const float* v1  = (const float*)d_in[13];
    const float* wdw = (const float*)d_in[14];
    const float* bdw = (const float*)d_in[15];
    const float* wpw = (const float*)d_in[16];
    const float* bpw = (const float*)d_in[17];
    const float* g2  = (const float*)d_in[18];
    const float* be2 = (const float*)d_in[19];
    const float* m2  = (const float*)d_in[20];
    const float* v2  = (const float*)d_in[21];
    const float* w3  = (const float*)d_in[22];
    const float* b3  = (const float*)d_in[23];
    const float* g3  = (const float*)d_in[24];
    const float* be3 = (const float*)d_in[25];
    const float* m3  = (const float*)d_in[26];
    const float* v3  = (const float*)d_in[27];

    float* ws  = (float*)d_ws;
    float* bev = ws;                              // [4,2,1024,1024] f32 (ws+0 .. 8388608)
    float* x1  = ws + 8388608;                    // [4,8,512,512] f32 (.. 16777216)
    float* x2  = bev;                             // [4,16,256,256] f32 (reuse ws+0 .. 4194304)
    _Float16* x3h = (_Float16*)(ws + 8388608);    // [4,256,256,32] f16 (overwrites x1, .. 12582912)
    // wh/tv live in the x2 region (dead after k_dwpw). k_wprep MUST run after k_dwpw:
    // running it earlier would be clobbered by k_conv1's x1 write (round-3 bug) or clobber bev/x2.
    _Float16* wh  = (_Float16*)ws;                // [9][64][32] f16 (ws+0 .. 9216 floats)
    float* tv  = ws + 9216;                       // [64] f32
    float* outp = (float*)d_out;                  // [4,64,128,128] f32

    k_init_bev<<<32768, 256, 0, stream>>>(bev);
    k_rasterize<<<(n + 255)/256, 256, 0, stream>>>(points, bev, n);
    k_conv1<<<4096, 256, 0, stream>>>(bev, w0, b0, g0, be0, m0, v0, x1);
    k_conv2<<<1024, 256, 0, stream>>>(x1, w1, b1, g1, be1, m1, v1, x2);
    k_dwpw<<<1024, 256, 0, stream>>>(x2, wdw, bdw, wpw, bpw, g2, be2, m2, v2, x3h);
    k_wprep<<<1, 256, 0, stream>>>(w3, b3, g3, be3, m3, v3, wh, tv);
    k_conv3m<<<512, 256, 0, stream>>>(x3h, wh, tv, outp);
}

// Round 5
// 264.250 us; speedup vs baseline: 2.5920x; 1.1021x over previous
//
#include <hip/hip_runtime.h>
#include <cstddef>

#define H_IN 1024
#define W_IN 1024
#define BN_EPS 1e-5f

typedef float f32x4 __attribute__((ext_vector_type(4)));
typedef _Float16 f16x8 __attribute__((ext_vector_type(8)));

__device__ __forceinline__ void atomicMaxF(float* addr, float val) {
    if (val >= 0.0f) {
        atomicMax((int*)addr, __float_as_int(val));
    } else {
        atomicMin((unsigned int*)addr, __float_as_uint(val));
    }
}

// ---------------- stage 0: BEV init + rasterize ----------------
__global__ void k_init_bev(float* __restrict__ bev) {
    size_t i = (size_t)blockIdx.x * blockDim.x + threadIdx.x;
    int plane = (int)((i >> 20) & 1);   // H*W = 2^20
    bev[i] = plane == 0 ? -10.0f : 0.0f;
}

__global__ void k_rasterize(const float* __restrict__ pts, float* __restrict__ bev, int n) {
    int i = blockIdx.x * blockDim.x + threadIdx.x;
    if (i >= n) return;
    float fb  = pts[(size_t)i*5+0];
    float px  = pts[(size_t)i*5+1];
    float py  = pts[(size_t)i*5+2];
    float pz  = pts[(size_t)i*5+3];
    float pit = pts[(size_t)i*5+4];
    const float XS = (float)(1024.0/69.12);
    const float YS = (float)(1024.0/79.36);
    int xp = (int)(px * XS);                  // trunc toward zero, same as astype(int32)
    int yp = (int)((py + 39.68f) * YS);
    if (xp < 0 || xp >= W_IN || yp < 0 || yp >= H_IN) return;
    int b = (int)fb;
    size_t off = (size_t)(b*2) * (H_IN*(size_t)W_IN) + (size_t)yp*W_IN + xp;
    atomicMaxF(bev + off, pz);
    atomicMaxF(bev + off + (size_t)H_IN*W_IN, pit);
}

// ---------------- stage 1: conv1(2->8,3x3,pad1)+BN+ReLU+maxpool2 ----------------
// in:  bev [4,2,1024,1024]   out: x1 [4,8,512,512]
__global__ __launch_bounds__(256, 4) void k_conv1(
                        const float* __restrict__ bev, const float* __restrict__ w0,
                        const float* __restrict__ b0, const float* __restrict__ g0,
                        const float* __restrict__ be0, const float* __restrict__ m0,
                        const float* __restrict__ v0, float* __restrict__ out) {
    __shared__ float wS[144];       // [8][2][3][3]
    __shared__ float sS[8], tS[8];
    int t = threadIdx.x;
    if (t < 144) wS[t] = w0[t];
    if (t < 8) {
        float s = g0[t] / sqrtf(v0[t] + BN_EPS);
        sS[t] = s;
        tS[t] = (b0[t] - m0[t]) * s + be0[t];
    }
    __syncthreads();
    int idx = blockIdx.x * 256 + t;                 // 4*512*512 total
    int x = idx & 511, y = (idx >> 9) & 511, b = idx >> 18;
    const float* base = bev + (size_t)b * 2 * H_IN * W_IN;
    float in[2][4][4];
    #pragma unroll
    for (int c = 0; c < 2; c++)
        #pragma unroll
        for (int r = 0; r < 4; r++) {
            int iy = 2*y - 1 + r;
            #pragma unroll
            for (int cc = 0; cc < 4; cc++) {
                int ix = 2*x - 1 + cc;
                in[c][r][cc] = (iy >= 0 && iy < H_IN && ix >= 0 && ix < W_IN)
                    ? base[(size_t)c*H_IN*W_IN + (size_t)iy*W_IN + ix] : 0.0f;
            }
        }
    float* ob = out + (size_t)b * 8 * 512 * 512 + (size_t)y*512 + x;
    #pragma unroll
    for (int oc = 0; oc < 8; oc++) {
        float mx = 0.0f;                            // post-ReLU values are >= 0
        #pragma unroll
        for (int py = 0; py < 2; py++)
            #pragma unroll
            for (int px = 0; px < 2; px++) {
                float acc = 0.0f;
                #pragma unroll
                for (int c = 0; c < 2; c++)
                    #pragma unroll
                    for (int kh = 0; kh < 3; kh++)
                        #pragma unroll
                        for (int kw = 0; kw < 3; kw++)
                            acc += in[c][py+kh][px+kw] * wS[((oc*2+c)*3+kh)*3+kw];
                acc = fmaxf(acc * sS[oc] + tS[oc], 0.0f);
                mx = fmaxf(mx, acc);
            }
        ob[(size_t)oc*512*512] = mx;
    }
}

// ---------------- stage 2: conv2 grouped(8)+BN+ReLU+maxpool2 ----------------
// in: x1 [4,8,512,512]   out: x2 [4,16,256,256]   (oc reads ic = oc>>1)
__global__ __launch_bounds__(256, 4) void k_conv2(
                        const float* __restrict__ x1, const float* __restrict__ w1,
                        const float* __restrict__ b1, const float* __restrict__ g1,
                        const float* __restrict__ be1, const float* __restrict__ m1,
                        const float* __restrict__ v1, float* __restrict__ out) {
    __shared__ float wS[144];       // [16][3][3]
    __shared__ float sS[16], tS[16];
    int t = threadIdx.x;
    if (t < 144) wS[t] = w1[t];
    if (t < 16) {
        float s = g1[t] / sqrtf(v1[t] + BN_EPS);
        sS[t] = s;
        tS[t] = (b1[t] - m1[t]) * s + be1[t];
    }
    __syncthreads();
    int idx = blockIdx.x * 256 + t;                 // 4*256*256 total
    int x = idx & 255, y = (idx >> 8) & 255, b = idx >> 16;
    const float* base = x1 + (size_t)b * 8 * 512 * 512;
    float* ob = out + (size_t)b * 16 * 256 * 256 + (size_t)y*256 + x;
    #pragma unroll
    for (int g = 0; g < 8; g++) {
        float p[4][4];
        #pragma unroll
        for (int r = 0; r < 4; r++) {
            int iy = 2*y - 1 + r;
            #pragma unroll
            for (int c = 0; c < 4; c++) {
                int ix = 2*x - 1 + c;
                p[r][c] = (iy >= 0 && iy < 512 && ix >= 0 && ix < 512)
                    ? base[(size_t)g*512*512 + (size_t)iy*512 + ix] : 0.0f;
            }
        }
        #pragma unroll
        for (int sub = 0; sub < 2; sub++) {
            int oc = g*2 + sub;
            float mx = 0.0f;
            #pragma unroll
            for (int py = 0; py < 2; py++)
                #pragma unroll
                for (int px = 0; px < 2; px++) {
                    float acc = 0.0f;
                    #pragma unroll
                    for (int kh = 0; kh < 3; kh++)
                        #pragma unroll
                        for (int kw = 0; kw < 3; kw++)
                            acc += p[py+kh][px+kw] * wS[(oc*3+kh)*3+kw];
                    acc = fmaxf(acc * sS[oc] + tS[oc], 0.0f);
                    mx = fmaxf(mx, acc);
                }
            ob[(size_t)oc*256*256] = mx;
        }
    }
}

// ---------------- stage 3: depthwise + pointwise + BN + ReLU -> f16 NHWC ----------------
// in: x2 [4,16,256,256] f32   out: x3h [4,256,256,32] f16
// __launch_bounds__(256,4): default 64-VGPR cap caused scratch spill (r4: 489MB HBM traffic)
__global__ __launch_bounds__(256, 4) void k_dwpw(
                       const float* __restrict__ x2, const float* __restrict__ wdw,
                       const float* __restrict__ bdw, const float* __restrict__ wpw,
                       const float* __restrict__ bpw, const float* __restrict__ g2,
                       const float* __restrict__ be2, const float* __restrict__ m2,
                       const float* __restrict__ v2, _Float16* __restrict__ out) {
    __shared__ float wdwS[144];     // [16][3][3]
    __shared__ float bdwS[16];
    __shared__ float wpwS[512];     // [32][16]
    __shared__ float sS[32], tS[32];
    int t = threadIdx.x;
    if (t < 144) wdwS[t] = wdw[t];
    if (t < 16) bdwS[t] = bdw[t];
    for (int i = t; i < 512; i += 256) wpwS[i] = wpw[i];
    if (t < 32) {
        float s = g2[t] / sqrtf(v2[t] + BN_EPS);
        sS[t] = s;
        tS[t] = (bpw[t] - m2[t]) * s + be2[t];
    }
    __syncthreads();
    int idx = blockIdx.x * 256 + t;                 // 4*256*256 total
    int x = idx & 255, y = (idx >> 8) & 255, b = idx >> 16;
    const float* base = x2 + (size_t)b * 16 * 256 * 256;

    // depthwise: 16 values, fully static indexing -> registers
    float dv[16];
    #pragma unroll
    for (int ic = 0; ic < 16; ic++) {
        float d = bdwS[ic];
        #pragma unroll
        for (int kh = 0; kh < 3; kh++) {
            int iy = y - 1 + kh;
            #pragma unroll
            for (int kw = 0; kw < 3; kw++) {
                int ix = x - 1 + kw;
                float v = (iy >= 0 && iy < 256 && ix >= 0 && ix < 256)
                    ? base[(size_t)ic*256*256 + (size_t)iy*256 + ix] : 0.0f;
                d += v * wdwS[(ic*3+kh)*3+kw];
            }
        }
        dv[ic] = d;
    }

    // pointwise -> f16 NHWC; store each 8-oc group immediately (small live set)
    _Float16* ob = out + ((size_t)((b*256 + y)*256 + x)) * 32;
    #pragma unroll
    for (int q = 0; q < 4; q++) {
        f16x8 ov;
        #pragma unroll
        for (int j = 0; j < 8; j++) {
            int oc = q*8 + j;
            float a = 0.0f;
            #pragma unroll
            for (int ic = 0; ic < 16; ic++)
                a += dv[ic] * wpwS[oc*16+ic];
            ov[j] = (_Float16)fmaxf(a*sS[oc] + tS[oc], 0.0f);
        }
        *(f16x8*)(ob + q*8) = ov;
    }
}

// ---------------- weight prep for conv3 MFMA ----------------
// wh[khw][oc][ic] f16 = w3[oc][ic][kh][kw] * s[oc];  tv[oc] = (b3-m3)*s + be3
__global__ void k_wprep(const float* __restrict__ w3, const float* __restrict__ b3,
                        const float* __restrict__ g3, const float* __restrict__ be3,
                        const float* __restrict__ m3, const float* __restrict__ v3,
                        _Float16* __restrict__ wh, float* __restrict__ tv) {
    int t = threadIdx.x;
    for (int i = t; i < 9*64*32; i += 256) {
        int khw = i >> 11;          // / (64*32)
        int rem = i & 2047;
        int oc = rem >> 5, ic = rem & 31;
        int kh = khw / 3, kw = khw % 3;
        float s = g3[oc] / sqrtf(v3[oc] + BN_EPS);
        wh[i] = (_Float16)(w3[((oc*32 + ic)*3 + kh)*3 + kw] * s);
    }
    if (t < 64) {
        float s = g3[t] / sqrtf(v3[t] + BN_EPS);
        tv[t] = (b3[t] - m3[t]) * s + be3[t];
    }
}

// ---------------- stage 4: conv3 via MFMA f16 implicit GEMM + BN + ReLU + maxpool2 ----------------
// in: x3h [4,256,256,32] f16 NHWC, wh [9][64][32] f16, tv[64] f32
// out: d_out [4,64,128,128] f32
// grid: 512 blocks = 4 xt * 32 yg * 4 b; block = 4 waves; each block: 4 y-pair tiles
// tile = pre-pool 2 rows x 64 cols; wave w owns x-slice [w*16, w*16+16)
__global__ __launch_bounds__(256, 2) void k_conv3m(const _Float16* __restrict__ xh,
                                                   const _Float16* __restrict__ wh,
                                                   const float* __restrict__ tv,
                                                   float* __restrict__ out) {
    __shared__ _Float16 As[4*66*40];        // rows x px x ic(pad 32->40), 21120 B
    int t = threadIdx.x;
    int lane = t & 63, w = t >> 6;
    int l15 = lane & 15, l4 = lane >> 4;
    int bi = blockIdx.x;
    int xt = bi & 3, yg = (bi >> 2) & 31, b = bi >> 7;
    int x0 = xt * 64;

    // B fragments: weights, held in VGPRs for the whole block (36 x f16x8 = 144 VGPR)
    f16x8 Bf[9][4];
    #pragma unroll
    for (int khw = 0; khw < 9; khw++)
        #pragma unroll
        for (int g = 0; g < 4; g++)
            Bf[khw][g] = *(const f16x8*)(wh + ((khw*64 + g*16 + l15)*32 + 8*l4));

    float tvv[4];
    #pragma unroll
    for (int g = 0; g < 4; g++) tvv[g] = tv[g*16 + l15];

    for (int ti = 0; ti < 4; ti++) {
        int ypool = yg*4 + ti;              // pooled row 0..127
        int y0 = ypool*2;
        __syncthreads();                    // wait: all waves done reading As (prev tile)
        // stage A: rows y0-1..y0+2, px 0..65 (global x = x0-1+px), 32 ic each
        for (int s = t; s < 264; s += 256) {
            int row = s / 66, px = s % 66;
            int gy = y0 - 1 + row, gx = x0 - 1 + px;
            float4* dst = (float4*)&As[(row*66 + px)*40];
            if (gy >= 0 && gy < 256 && gx >= 0 && gx < 256) {
                const float4* src = (const float4*)(xh + ((size_t)((b*256 + gy)*256 + gx)) * 32);
                #pragma unroll
                for (int j = 0; j < 4; j++) dst[j] = src[j];
            } else {
                float4 z = make_float4(0.f, 0.f, 0.f, 0.f);
                #pragma unroll
                for (int j = 0; j < 4; j++) dst[j] = z;
            }
        }
        __syncthreads();

        f32x4 acc[2][4];
        #pragma unroll
        for (int f = 0; f < 2; f++)
            #pragma unroll
            for (int g = 0; g < 4; g++)
                acc[f][g] = (f32x4){0.f, 0.f, 0.f, 0.f};

        #pragma unroll
        for (int kh = 0; kh < 3; kh++)
            #pragma unroll
            for (int kw = 0; kw < 3; kw++) {
                f16x8 Af[2];
                #pragma unroll
                for (int f = 0; f < 2; f++) {
                    int row = f + kh;                       // staged row idx
                    int px = w*16 + l15 + kw;               // staged px idx
                    Af[f] = *(const f16x8*)&As[(row*66 + px)*40 + 8*l4];
                }
                #pragma unroll
                for (int f = 0; f < 2; f++)
                    #pragma unroll
                    for (int g = 0; g < 4; g++)
                        acc[f][g] = __builtin_amdgcn_mfma_f32_16x16x32_f16(
                            Af[f], Bf[kh*3+kw][g], acc[f][g], 0, 0, 0);
            }

        // epilogue: bias + relu + 2x2 maxpool (all in-lane), store
        #pragma unroll
        for (int g = 0; g < 4; g++) {
            int oc = g*16 + l15;
            #pragma unroll
            for (int q = 0; q < 2; q++) {
                float v0 = fmaxf(fmaxf(acc[0][g][2*q]   + tvv[g], 0.f),
                                 fmaxf(acc[0][g][2*q+1] + tvv[g], 0.f));
                float v1 = fmaxf(fmaxf(acc[1][g][2*q]   + tvv[g], 0.f),
                                 fmaxf(acc[1][g][2*q+1] + tvv[g], 0.f));
                int px = x0/2 + w*8 + 2*l4 + q;
                out[(((size_t)b*64 + oc)*128 + ypool)*128 + px] = fmaxf(v0, v1);
            }
        }
    }
}

extern "C" void kernel_launch(void* const* d_in, const int* in_sizes, int n_in,
                              void* d_out, int out_size, void* d_ws, size_t ws_size,
                              hipStream_t stream) {
    const float* points = (const float*)d_in[0];
    int n = in_sizes[0] / 5;
    const float* w0  = (const float*)d_in[2];
    const float* b0  = (const float*)d_in[3];
    const float* g0  = (const float*)d_in[4];
    const float* be0 = (const float*)d_in[5];
    const float* m0  = (const float*)d_in[6];
    const float* v0  = (const float*)d_in[7];
    const float* w1  = (const float*)d_in[8];
    const float* b1  = (const float*)d_in[9];
    const float* g1  = (const float*)d_in[10];
    const float* be1 = (const float*)d_in[11];
    const float* m1  = (const float*)d_in[12];
    const float* v1  = (const float*)d_in[13];
    const float* wdw = (const float*)d_in[14];
    const float* bdw = (const float*)d_in[15];
    const float* wpw = (const float*)d_in[16];
    const float* bpw = (const float*)d_in[17];
    const float* g2  = (const float*)d_in[18];
    const float* be2 = (const float*)d_in[19];
    const float* m2  = (const float*)d_in[20];
    const float* v2  = (const float*)d_in[21];
    const float* w3  = (const float*)d_in[22];
    const float* b3  = (const float*)d_in[23];
    const float* g3  = (const float*)d_in[24];
    const float* be3 = (const float*)d_in[25];
    const float* m3  = (const float*)d_in[26];
    const float* v3  = (const float*)d_in[27];

    float* ws  = (float*)d_ws;
    float* bev = ws;                              // [4,2,1024,1024] f32 (ws+0 .. 8388608)
    float* x1  = ws + 8388608;                    // [4,8,512,512] f32 (.. 16777216)
    float* x2  = bev;                             // [4,16,256,256] f32 (reuse ws+0 .. 4194304)
    _Float16* x3h = (_Float16*)(ws + 8388608);    // [4,256,256,32] f16 (overwrites x1, .. 12582912)
    // wh/tv live in the x2 region (dead after k_dwpw). k_wprep MUST run after k_dwpw.
    _Float16* wh  = (_Float16*)ws;                // [9][64][32] f16 (ws+0 .. 9216 floats)
    float* tv  = ws + 9216;                       // [64] f32
    float* outp = (float*)d_out;                  // [4,64,128,128] f32

    k_init_bev<<<32768, 256, 0, stream>>>(bev);
    k_rasterize<<<(n + 255)/256, 256, 0, stream>>>(points, bev, n);
    k_conv1<<<4096, 256, 0, stream>>>(bev, w0, b0, g0, be0, m0, v0, x1);
    k_conv2<<<1024, 256, 0, stream>>>(x1, w1, b1, g1, be1, m1, v1, x2);
    k_dwpw<<<1024, 256, 0, stream>>>(x2, wdw, bdw, wpw, bpw, g2, be2, m2, v2, x3h);
    k_wprep<<<1, 256, 0, stream>>>(w3, b3, g3, be3, m3, v3, wh, tv);
    k_conv3m<<<512, 256, 0, stream>>>(x3h, wh, tv, outp);
}

// Round 6
// 151.368 us; speedup vs baseline: 4.5250x; 1.7457x over previous
//
#include <hip/hip_runtime.h>
#include <cstddef>

#define H_IN 1024
#define W_IN 1024
#define BN_EPS 1e-5f

typedef float f32x4 __attribute__((ext_vector_type(4)));
typedef _Float16 f16x8 __attribute__((ext_vector_type(8)));

__device__ __forceinline__ void atomicMaxF(float* addr, float val) {
    if (val >= 0.0f) {
        atomicMax((int*)addr, __float_as_int(val));
    } else {
        atomicMin((unsigned int*)addr, __float_as_uint(val));
    }
}

// ---------------- stage 0: BEV init + rasterize ----------------
__global__ void k_init_bev(float* __restrict__ bev) {
    size_t i = (size_t)blockIdx.x * blockDim.x + threadIdx.x;
    int plane = (int)((i >> 20) & 1);   // H*W = 2^20
    bev[i] = plane == 0 ? -10.0f : 0.0f;
}

__global__ void k_rasterize(const float* __restrict__ pts, float* __restrict__ bev, int n) {
    int i = blockIdx.x * blockDim.x + threadIdx.x;
    if (i >= n) return;
    float fb  = pts[(size_t)i*5+0];
    float px  = pts[(size_t)i*5+1];
    float py  = pts[(size_t)i*5+2];
    float pz  = pts[(size_t)i*5+3];
    float pit = pts[(size_t)i*5+4];
    const float XS = (float)(1024.0/69.12);
    const float YS = (float)(1024.0/79.36);
    int xp = (int)(px * XS);                  // trunc toward zero, same as astype(int32)
    int yp = (int)((py + 39.68f) * YS);
    if (xp < 0 || xp >= W_IN || yp < 0 || yp >= H_IN) return;
    int b = (int)fb;
    size_t off = (size_t)(b*2) * (H_IN*(size_t)W_IN) + (size_t)yp*W_IN + xp;
    atomicMaxF(bev + off, pz);
    atomicMaxF(bev + off + (size_t)H_IN*W_IN, pit);
}

// ---------------- stage 1: conv1(2->8,3x3,pad1)+BN+ReLU+maxpool2 ----------------
// in:  bev [4,2,1024,1024]   out: x1 [4,8,512,512]
__global__ __launch_bounds__(256, 4) void k_conv1(
                        const float* __restrict__ bev, const float* __restrict__ w0,
                        const float* __restrict__ b0, const float* __restrict__ g0,
                        const float* __restrict__ be0, const float* __restrict__ m0,
                        const float* __restrict__ v0, float* __restrict__ out) {
    __shared__ float wS[144];       // [8][2][3][3]
    __shared__ float sS[8], tS[8];
    int t = threadIdx.x;
    if (t < 144) wS[t] = w0[t];
    if (t < 8) {
        float s = g0[t] / sqrtf(v0[t] + BN_EPS);
        sS[t] = s;
        tS[t] = (b0[t] - m0[t]) * s + be0[t];
    }
    __syncthreads();
    int idx = blockIdx.x * 256 + t;                 // 4*512*512 total
    int x = idx & 511, y = (idx >> 9) & 511, b = idx >> 18;
    const float* base = bev + (size_t)b * 2 * H_IN * W_IN;
    float in[2][4][4];
    #pragma unroll
    for (int c = 0; c < 2; c++)
        #pragma unroll
        for (int r = 0; r < 4; r++) {
            int iy = 2*y - 1 + r;
            #pragma unroll
            for (int cc = 0; cc < 4; cc++) {
                int ix = 2*x - 1 + cc;
                in[c][r][cc] = (iy >= 0 && iy < H_IN && ix >= 0 && ix < W_IN)
                    ? base[(size_t)c*H_IN*W_IN + (size_t)iy*W_IN + ix] : 0.0f;
            }
        }
    float* ob = out + (size_t)b * 8 * 512 * 512 + (size_t)y*512 + x;
    #pragma unroll
    for (int oc = 0; oc < 8; oc++) {
        float mx = 0.0f;                            // post-ReLU values are >= 0
        #pragma unroll
        for (int py = 0; py < 2; py++)
            #pragma unroll
            for (int px = 0; px < 2; px++) {
                float acc = 0.0f;
                #pragma unroll
                for (int c = 0; c < 2; c++)
                    #pragma unroll
                    for (int kh = 0; kh < 3; kh++)
                        #pragma unroll
                        for (int kw = 0; kw < 3; kw++)
                            acc += in[c][py+kh][px+kw] * wS[((oc*2+c)*3+kh)*3+kw];
                acc = fmaxf(acc * sS[oc] + tS[oc], 0.0f);
                mx = fmaxf(mx, acc);
            }
        ob[(size_t)oc*512*512] = mx;
    }
}

// ---------------- stage 2: conv2 grouped(8)+BN+ReLU+maxpool2 ----------------
// in: x1 [4,8,512,512]   out: x2 [4,16,256,256]   (oc reads ic = oc>>1)
__global__ __launch_bounds__(256, 4) void k_conv2(
                        const float* __restrict__ x1, const float* __restrict__ w1,
                        const float* __restrict__ b1, const float* __restrict__ g1,
                        const float* __restrict__ be1, const float* __restrict__ m1,
                        const float* __restrict__ v1, float* __restrict__ out) {
    __shared__ float wS[144];       // [16][3][3]
    __shared__ float sS[16], tS[16];
    int t = threadIdx.x;
    if (t < 144) wS[t] = w1[t];
    if (t < 16) {
        float s = g1[t] / sqrtf(v1[t] + BN_EPS);
        sS[t] = s;
        tS[t] = (b1[t] - m1[t]) * s + be1[t];
    }
    __syncthreads();
    int idx = blockIdx.x * 256 + t;                 // 4*256*256 total
    int x = idx & 255, y = (idx >> 8) & 255, b = idx >> 16;
    const float* base = x1 + (size_t)b * 8 * 512 * 512;
    float* ob = out + (size_t)b * 16 * 256 * 256 + (size_t)y*256 + x;
    #pragma unroll
    for (int g = 0; g < 8; g++) {
        float p[4][4];
        #pragma unroll
        for (int r = 0; r < 4; r++) {
            int iy = 2*y - 1 + r;
            #pragma unroll
            for (int c = 0; c < 4; c++) {
                int ix = 2*x - 1 + c;
                p[r][c] = (iy >= 0 && iy < 512 && ix >= 0 && ix < 512)
                    ? base[(size_t)g*512*512 + (size_t)iy*512 + ix] : 0.0f;
            }
        }
        #pragma unroll
        for (int sub = 0; sub < 2; sub++) {
            int oc = g*2 + sub;
            float mx = 0.0f;
            #pragma unroll
            for (int py = 0; py < 2; py++)
                #pragma unroll
                for (int px = 0; px < 2; px++) {
                    float acc = 0.0f;
                    #pragma unroll
                    for (int kh = 0; kh < 3; kh++)
                        #pragma unroll
                        for (int kw = 0; kw < 3; kw++)
                            acc += p[py+kh][px+kw] * wS[(oc*3+kh)*3+kw];
                    acc = fmaxf(acc * sS[oc] + tS[oc], 0.0f);
                    mx = fmaxf(mx, acc);
                }
            ob[(size_t)oc*256*256] = mx;
        }
    }
}

// ---------------- stage 3: depthwise + pointwise + BN + ReLU -> f16 NHWC ----------------
// in: x2 [4,16,256,256] f32   out: x3h [4,256,256,32] f16
// LDS-tiled rewrite (r5): block = 32x8 pixel tile; stage 16ic x 10row x 34col halo patch
// into LDS (each global element read EXACTLY once, coalesced). Kills the 9.5x read /
// 16x write HBM amplification seen in r4/r5 profiles. Register footprint ~30 VGPRs.
__global__ __launch_bounds__(256, 4) void k_dwpw(
                       const float* __restrict__ x2, const float* __restrict__ wdw,
                       const float* __restrict__ bdw, const float* __restrict__ wpw,
                       const float* __restrict__ bpw, const float* __restrict__ g2,
                       const float* __restrict__ be2, const float* __restrict__ m2,
                       const float* __restrict__ v2, _Float16* __restrict__ out) {
    __shared__ float patch[16*10*36];   // [ic][row 10][col 34 pad->36] = 23040 B
    __shared__ float wdwS[144];         // [16][3][3]
    __shared__ float bdwS[16];
    __shared__ float wpwS[512];         // [32][16]
    __shared__ float sS[32], tS[32];
    int t = threadIdx.x;
    if (t < 144) wdwS[t] = wdw[t];
    if (t < 16) bdwS[t] = bdw[t];
    for (int i = t; i < 512; i += 256) wpwS[i] = wpw[i];
    if (t < 32) {
        float s = g2[t] / sqrtf(v2[t] + BN_EPS);
        sS[t] = s;
        tS[t] = (bpw[t] - m2[t]) * s + be2[t];
    }

    int bi = blockIdx.x;                 // 1024 = 8 tx * 32 ty * 4 b
    int tx = bi & 7, ty = (bi >> 3) & 31, b = bi >> 8;
    int x0 = tx * 32, y0 = ty * 8;
    const float* base = x2 + (size_t)b * 16 * 256 * 256;

    // stage: 16 ic x 10 rows x 34 cols, one global read per element
    for (int i = t; i < 16*10*34; i += 256) {
        int ic = i / 340;
        int rem = i - ic * 340;
        int r = rem / 34, c = rem - r * 34;
        int gy = y0 - 1 + r, gx = x0 - 1 + c;
        patch[(ic*10 + r)*36 + c] =
            (gy >= 0 && gy < 256 && gx >= 0 && gx < 256)
                ? base[(size_t)ic*65536 + (size_t)gy*256 + gx] : 0.0f;
    }
    __syncthreads();

    int px = t & 31, pyy = t >> 5;       // pixel within tile
    int x = x0 + px, y = y0 + pyy;

    // depthwise from LDS: taps patch[ic][pyy+r][px+c]
    float dv[16];
    #pragma unroll
    for (int ic = 0; ic < 16; ic++) {
        float d = bdwS[ic];
        #pragma unroll
        for (int r = 0; r < 3; r++)
            #pragma unroll
            for (int c = 0; c < 3; c++)
                d += patch[(ic*10 + pyy + r)*36 + px + c] * wdwS[ic*9 + r*3 + c];
        dv[ic] = d;
    }

    // pointwise -> f16 NHWC; store each 8-oc group immediately
    _Float16* ob = out + ((size_t)((b*256 + y)*256 + x)) * 32;
    #pragma unroll
    for (int q = 0; q < 4; q++) {
        f16x8 ov;
        #pragma unroll
        for (int j = 0; j < 8; j++) {
            int oc = q*8 + j;
            float a = 0.0f;
            #pragma unroll
            for (int ic = 0; ic < 16; ic++)
                a += dv[ic] * wpwS[oc*16+ic];
            ov[j] = (_Float16)fmaxf(a*sS[oc] + tS[oc], 0.0f);
        }
        *(f16x8*)(ob + q*8) = ov;
    }
}

// ---------------- weight prep for conv3 MFMA ----------------
// wh[khw][oc][ic] f16 = w3[oc][ic][kh][kw] * s[oc];  tv[oc] = (b3-m3)*s + be3
__global__ void k_wprep(const float* __restrict__ w3, const float* __restrict__ b3,
                        const float* __restrict__ g3, const float* __restrict__ be3,
                        const float* __restrict__ m3, const float* __restrict__ v3,
                        _Float16* __restrict__ wh, float* __restrict__ tv) {
    int t = threadIdx.x;
    for (int i = t; i < 9*64*32; i += 256) {
        int khw = i >> 11;          // / (64*32)
        int rem = i & 2047;
        int oc = rem >> 5, ic = rem & 31;
        int kh = khw / 3, kw = khw % 3;
        float s = g3[oc] / sqrtf(v3[oc] + BN_EPS);
        wh[i] = (_Float16)(w3[((oc*32 + ic)*3 + kh)*3 + kw] * s);
    }
    if (t < 64) {
        float s = g3[t] / sqrtf(v3[t] + BN_EPS);
        tv[t] = (b3[t] - m3[t]) * s + be3[t];
    }
}

// ---------------- stage 4: conv3 via MFMA f16 implicit GEMM + BN + ReLU + maxpool2 ----------------
// in: x3h [4,256,256,32] f16 NHWC, wh [9][64][32] f16, tv[64] f32
// out: d_out [4,64,128,128] f32
// grid: 512 blocks = 4 xt * 32 yg * 4 b; block = 4 waves; each block: 4 y-pair tiles
// tile = pre-pool 2 rows x 64 cols; wave w owns x-slice [w*16, w*16+16)
__global__ __launch_bounds__(256, 2) void k_conv3m(const _Float16* __restrict__ xh,
                                                   const _Float16* __restrict__ wh,
                                                   const float* __restrict__ tv,
                                                   float* __restrict__ out) {
    __shared__ _Float16 As[4*66*40];        // rows x px x ic(pad 32->40), 21120 B
    int t = threadIdx.x;
    int lane = t & 63, w = t >> 6;
    int l15 = lane & 15, l4 = lane >> 4;
    int bi = blockIdx.x;
    int xt = bi & 3, yg = (bi >> 2) & 31, b = bi >> 7;
    int x0 = xt * 64;

    // B fragments: weights, held in VGPRs for the whole block (36 x f16x8 = 144 VGPR)
    f16x8 Bf[9][4];
    #pragma unroll
    for (int khw = 0; khw < 9; khw++)
        #pragma unroll
        for (int g = 0; g < 4; g++)
            Bf[khw][g] = *(const f16x8*)(wh + ((khw*64 + g*16 + l15)*32 + 8*l4));

    float tvv[4];
    #pragma unroll
    for (int g = 0; g < 4; g++) tvv[g] = tv[g*16 + l15];

    for (int ti = 0; ti < 4; ti++) {
        int ypool = yg*4 + ti;              // pooled row 0..127
        int y0 = ypool*2;
        __syncthreads();                    // wait: all waves done reading As (prev tile)
        // stage A: rows y0-1..y0+2, px 0..65 (global x = x0-1+px), 32 ic each
        for (int s = t; s < 264; s += 256) {
            int row = s / 66, px = s % 66;
            int gy = y0 - 1 + row, gx = x0 - 1 + px;
            float4* dst = (float4*)&As[(row*66 + px)*40];
            if (gy >= 0 && gy < 256 && gx >= 0 && gx < 256) {
                const float4* src = (const float4*)(xh + ((size_t)((b*256 + gy)*256 + gx)) * 32);
                #pragma unroll
                for (int j = 0; j < 4; j++) dst[j] = src[j];
            } else {
                float4 z = make_float4(0.f, 0.f, 0.f, 0.f);
                #pragma unroll
                for (int j = 0; j < 4; j++) dst[j] = z;
            }
        }
        __syncthreads();

        f32x4 acc[2][4];
        #pragma unroll
        for (int f = 0; f < 2; f++)
            #pragma unroll
            for (int g = 0; g < 4; g++)
                acc[f][g] = (f32x4){0.f, 0.f, 0.f, 0.f};

        #pragma unroll
        for (int kh = 0; kh < 3; kh++)
            #pragma unroll
            for (int kw = 0; kw < 3; kw++) {
                f16x8 Af[2];
                #pragma unroll
                for (int f = 0; f < 2; f++) {
                    int row = f + kh;                       // staged row idx
                    int px = w*16 + l15 + kw;               // staged px idx
                    Af[f] = *(const f16x8*)&As[(row*66 + px)*40 + 8*l4];
                }
                #pragma unroll
                for (int f = 0; f < 2; f++)
                    #pragma unroll
                    for (int g = 0; g < 4; g++)
                        acc[f][g] = __builtin_amdgcn_mfma_f32_16x16x32_f16(
                            Af[f], Bf[kh*3+kw][g], acc[f][g], 0, 0, 0);
            }

        // epilogue: bias + relu + 2x2 maxpool (all in-lane), store
        #pragma unroll
        for (int g = 0; g < 4; g++) {
            int oc = g*16 + l15;
            #pragma unroll
            for (int q = 0; q < 2; q++) {
                float v0 = fmaxf(fmaxf(acc[0][g][2*q]   + tvv[g], 0.f),
                                 fmaxf(acc[0][g][2*q+1] + tvv[g], 0.f));
                float v1 = fmaxf(fmaxf(acc[1][g][2*q]   + tvv[g], 0.f),
                                 fmaxf(acc[1][g][2*q+1] + tvv[g], 0.f));
                int px = x0/2 + w*8 + 2*l4 + q;
                out[(((size_t)b*64 + oc)*128 + ypool)*128 + px] = fmaxf(v0, v1);
            }
        }
    }
}

extern "C" void kernel_launch(void* const* d_in, const int* in_sizes, int n_in,
                              void* d_out, int out_size, void* d_ws, size_t ws_size,
                              hipStream_t stream) {
    const float* points = (const float*)d_in[0];
    int n = in_sizes[0] / 5;
    const float* w0  = (const float*)d_in[2];
    const float* b0  = (const float*)d_in[3];
    const float* g0  = (const float*)d_in[4];
    const float* be0 = (const float*)d_in[5];
    const float* m0  = (const float*)d_in[6];
    const float* v0  = (const float*)d_in[7];
    const float* w1  = (const float*)d_in[8];
    const float* b1  = (const float*)d_in[9];
    const float* g1  = (const float*)d_in[10];
    const float* be1 = (const float*)d_in[11];
    const float* m1  = (const float*)d_in[12];
    const float* v1  = (const float*)d_in[13];
    const float* wdw = (const float*)d_in[14];
    const float* bdw = (const float*)d_in[15];
    const float* wpw = (const float*)d_in[16];
    const float* bpw = (const float*)d_in[17];
    const float* g2  = (const float*)d_in[18];
    const float* be2 = (const float*)d_in[19];
    const float* m2  = (const float*)d_in[20];
    const float* v2  = (const float*)d_in[21];
    const float* w3  = (const float*)d_in[22];
    const float* b3  = (const float*)d_in[23];
    const float* g3  = (const float*)d_in[24];
    const float* be3 = (const float*)d_in[25];
    const float* m3  = (const float*)d_in[26];
    const float* v3  = (const float*)d_in[27];

    float* ws  = (float*)d_ws;
    float* bev = ws;                              // [4,2,1024,1024] f32 (ws+0 .. 8388608)
    float* x1  = ws + 8388608;                    // [4,8,512,512] f32 (.. 16777216)
    float* x2  = bev;                             // [4,16,256,256] f32 (reuse ws+0 .. 4194304)
    _Float16* x3h = (_Float16*)(ws + 8388608);    // [4,256,256,32] f16 (overwrites x1, .. 12582912)
    // wh/tv live in the x2 region (dead after k_dwpw). k_wprep MUST run after k_dwpw.
    _Float16* wh  = (_Float16*)ws;                // [9][64][32] f16 (ws+0 .. 9216 floats)
    float* tv  = ws + 9216;                       // [64] f32
    float* outp = (float*)d_out;                  // [4,64,128,128] f32

    k_init_bev<<<32768, 256, 0, stream>>>(bev);
    k_rasterize<<<(n + 255)/256, 256, 0, stream>>>(points, bev, n);
    k_conv1<<<4096, 256, 0, stream>>>(bev, w0, b0, g0, be0, m0, v0, x1);
    k_conv2<<<1024, 256, 0, stream>>>(x1, w1, b1, g1, be1, m1, v1, x2);
    k_dwpw<<<1024, 256, 0, stream>>>(x2, wdw, bdw, wpw, bpw, g2, be2, m2, v2, x3h);
    k_wprep<<<1, 256, 0, stream>>>(w3, b3, g3, be3, m3, v3, wh, tv);
    k_conv3m<<<512, 256, 0, stream>>>(x3h, wh, tv, outp);
}